// Round 9
// baseline (137.205 us; speedup 1.0000x reference)
//
#include <hip/hip_runtime.h>

#define NB 16384
#define XD 784
#define ZD 64
#define KK 64
#define LOG2PI_F 1.8378770664093453f

typedef __attribute__((ext_vector_type(8))) short short8;
typedef __attribute__((ext_vector_type(4))) float floatx4;

// ws layout (bytes):
//   [0      ,102400) : Wb16[64][800] bf16  (W cast, K-padded with zeros)
//   [102400 ,110592) : G2[64][64]   bf16  (W @ W^T)
//   [110592 ,118784) : Bi2[64][64]  bf16  (0.5*exp(-2*plog))
//   [118784 ,126976) : Bm1[64][64]  bf16  (pmu * i2)
//   [126976 ,127232) : Sk[64]  f32
//   [127232 ,127488) : Gk[64]  f32
//   [127488 ,127744) : Wbv[64] f32  (W @ b_dec)
//   [127744 ,127808) : sb2 f32 (sum b^2)
//   [127808 ,131904) : dec_p[1024] f32
//   [131904 ,136000) : kly_p[1024] f32
//   [136000 ,140096) : klz_p[1024] f32

__device__ __forceinline__ float wave_sum(float x) {
    #pragma unroll
    for (int o = 32; o > 0; o >>= 1) x += __shfl_xor(x, o, 64);
    return x;
}

__device__ __forceinline__ unsigned short f2bf(float f) {
    unsigned u = __float_as_uint(f);
    unsigned r = (u + 0x7FFF + ((u >> 16) & 1)) >> 16;  // RNE
    return (unsigned short)r;
}

__device__ __forceinline__ unsigned int pack2(float a, float b) {
    return (unsigned int)f2bf(a) | ((unsigned int)f2bf(b) << 16);
}

__device__ __forceinline__ short8 pack8(const float* v) {
    short8 r;
    unsigned int* p = (unsigned int*)&r;
    p[0] = pack2(v[0], v[1]);
    p[1] = pack2(v[2], v[3]);
    p[2] = pack2(v[4], v[5]);
    p[3] = pack2(v[6], v[7]);
    return r;
}

__device__ __forceinline__ float d4(float4 a, float4 b) {
    return a.x * b.x + a.y * b.y + a.z * b.z + a.w * b.w;
}

// blocks 0..199: Wb16 cast+pad. block 200: B tables. block 201: Wbv + sb2.
__global__ __launch_bounds__(256) void prep1_kernel(
    const float* __restrict__ W, const float* __restrict__ pmu_g,
    const float* __restrict__ plog_g, const float* __restrict__ bd,
    unsigned short* __restrict__ Wb16,
    unsigned short* __restrict__ Bi2, unsigned short* __restrict__ Bm1,
    float* __restrict__ Sk, float* __restrict__ Gk,
    float* __restrict__ Wbv, float* __restrict__ sb2)
{
    const int tid = threadIdx.x;
    if (blockIdx.x < 200) {
        int idx = blockIdx.x * 256 + tid;      // < 51200
        int v = idx / 800, c = idx - v * 800;
        Wb16[idx] = (c < XD) ? f2bf(W[v * XD + c]) : (unsigned short)0;
        return;
    }
    if (blockIdx.x == 200) {
        const int k  = tid >> 2;
        const int q  = tid & 3;
        const int v0 = q * 16;
        float s = 0.f, g = 0.f;
        unsigned int* pi2 = (unsigned int*)&Bi2[k * 64 + v0];
        unsigned int* pm1 = (unsigned int*)&Bm1[k * 64 + v0];
        #pragma unroll
        for (int i = 0; i < 4; ++i) {
            float4 mu4 = *(const float4*)&pmu_g[k * 64 + v0 + 4 * i];
            float4 lg4 = *(const float4*)&plog_g[k * 64 + v0 + 4 * i];
            float m0[4] = {mu4.x, mu4.y, mu4.z, mu4.w};
            float l0[4] = {lg4.x, lg4.y, lg4.z, lg4.w};
            float i2v[4], m1v[4];
            #pragma unroll
            for (int j = 0; j < 4; ++j) {
                float i2 = 0.5f * __expf(-2.f * l0[j]);
                i2v[j] = i2;
                m1v[j] = m0[j] * i2;
                g = fmaf(m0[j] * m0[j], i2, g);
                s += l0[j];
            }
            pi2[i * 2 + 0] = pack2(i2v[0], i2v[1]);
            pi2[i * 2 + 1] = pack2(i2v[2], i2v[3]);
            pm1[i * 2 + 0] = pack2(m1v[0], m1v[1]);
            pm1[i * 2 + 1] = pack2(m1v[2], m1v[3]);
        }
        s += __shfl_xor(s, 1, 64);
        s += __shfl_xor(s, 2, 64);
        g += __shfl_xor(g, 1, 64);
        g += __shfl_xor(g, 2, 64);
        if (q == 0) { Sk[k] = s; Gk[k] = g; }
        return;
    }
    // block 201: Wbv[v] = sum_j W[v,j]*bd[j];  sb2 = sum_j bd[j]^2
    __shared__ float wl[256], bl[256];
    const int v = tid & 63, p = tid >> 6;
    float s = 0.f;
    for (int j = p * 196; j < p * 196 + 196; ++j)
        s = fmaf(W[v * XD + j], bd[j], s);
    wl[tid] = s;
    float b2 = 0.f;
    for (int j = tid; j < XD; j += 256) b2 = fmaf(bd[j], bd[j], b2);
    bl[tid] = b2;
    __syncthreads();
    if (tid < 64) Wbv[tid] = wl[tid] + wl[64 + tid] + wl[128 + tid] + wl[192 + tid];
    if (tid < 32) {
        float t2 = 0.f;
        for (int i = tid; i < 256; i += 32) t2 += bl[i];
        #pragma unroll
        for (int o = 16; o > 0; o >>= 1) t2 += __shfl_xor(t2, o, 64);
        if (tid == 0) sb2[0] = t2;
    }
}

// G2 = W @ W^T via MFMA from padded Wb16 (K=800, pad zeros). 16 blocks x 1 wave.
__global__ __launch_bounds__(64) void prep2_kernel(
    const unsigned short* __restrict__ Wb16, unsigned short* __restrict__ G2)
{
    const int lane = threadIdx.x & 63;
    const int mm = lane & 15, q = lane >> 4;
    const int ti = blockIdx.x >> 2, tj = blockIdx.x & 3;
    floatx4 acc = {0.f, 0.f, 0.f, 0.f};
    #pragma unroll 5
    for (int kt = 0; kt < 25; ++kt) {
        const int kc = kt * 32 + q * 8;
        short8 a = *(const short8*)&Wb16[(ti * 16 + mm) * 800 + kc];
        short8 b = *(const short8*)&Wb16[(tj * 16 + mm) * 800 + kc];
        acc = __builtin_amdgcn_mfma_f32_16x16x32_bf16(a, b, acc, 0, 0, 0);
    }
    #pragma unroll
    for (int r = 0; r < 4; ++r)
        G2[(ti * 16 + q * 4 + r) * 64 + tj * 16 + mm] = f2bf(acc[r]);
}

// Mega kernel: 16 rows/block, 1024 blocks.
// Phase 1 (all 4 waves): XW = x @ W^T, waves split K (6 k-tiles each; wave 3
// takes the masked 7th). x streamed sequentially per row, all tiles preloaded.
// Also accumulates sum(x^2) and x.b per row. One barrier; LDS combine.
// Phase 2 (wave 0): mixture MFMAs + softmax + KLs, plus decoder scalars
// (z.XW, z G2 z via LDS C->A transform, z.Wb) -> per-block partials.
__global__ __launch_bounds__(256) void mega_kernel(
    const float* __restrict__ x, const float* __restrict__ pi,
    const float* __restrict__ qmu, const float* __restrict__ qls,
    const float* __restrict__ eps, const float* __restrict__ bd,
    const unsigned short* __restrict__ Wb16, const unsigned short* __restrict__ G2,
    const unsigned short* __restrict__ Bi2, const unsigned short* __restrict__ Bm1,
    const float* __restrict__ Sk, const float* __restrict__ Gk,
    const float* __restrict__ Wbv, const float* __restrict__ sb2p,
    float* __restrict__ dec_p, float* __restrict__ kly_p, float* __restrict__ klz_p)
{
    __shared__ float XWp[4][16][64];
    __shared__ float sxp[4][16], xbp[4][16];
    __shared__ float us[16][64];

    const int tid  = threadIdx.x;
    const int lane = tid & 63;
    const int wid  = tid >> 6;
    const int mm   = lane & 15;
    const int q    = lane >> 4;
    const int row0 = blockIdx.x * 16;

    // ---- phase 1: XW GEMM, K-chunk = tiles [wid*6, wid*6+6) (+ tile 24 on wave 3)
    const float* xrow = x + (row0 + mm) * XD;
    const int tbase = wid * 6;
    float sx2 = 0.f, xb = 0.f;
    short8 axf[6];
    #pragma unroll
    for (int i = 0; i < 6; ++i) {
        const int c = (tbase + i) * 32 + q * 8;
        float4 a0 = *(const float4*)&xrow[c];
        float4 a1 = *(const float4*)&xrow[c + 4];
        float4 b0 = *(const float4*)&bd[c];
        float4 b1 = *(const float4*)&bd[c + 4];
        sx2 += d4(a0, a0) + d4(a1, a1);
        xb  += d4(a0, b0) + d4(a1, b1);
        float tmp[8] = {a0.x, a0.y, a0.z, a0.w, a1.x, a1.y, a1.z, a1.w};
        axf[i] = pack8(tmp);
    }
    floatx4 acc[4] = {{0.f,0.f,0.f,0.f},{0.f,0.f,0.f,0.f},{0.f,0.f,0.f,0.f},{0.f,0.f,0.f,0.f}};
    #pragma unroll
    for (int i = 0; i < 6; ++i) {
        const int kc = (tbase + i) * 32 + q * 8;
        #pragma unroll
        for (int t = 0; t < 4; ++t) {
            short8 bfr = *(const short8*)&Wb16[(t * 16 + mm) * 800 + kc];
            acc[t] = __builtin_amdgcn_mfma_f32_16x16x32_bf16(axf[i], bfr, acc[t], 0, 0, 0);
        }
    }
    if (wid == 3) {   // masked tail tile 24: cols 768..799, valid < 784
        const int c = 768 + q * 8;
        const bool ok = q < 2;
        float4 z4 = {0.f, 0.f, 0.f, 0.f};
        float4 a0 = ok ? *(const float4*)&xrow[c]     : z4;
        float4 a1 = ok ? *(const float4*)&xrow[c + 4] : z4;
        float4 b0 = ok ? *(const float4*)&bd[c]       : z4;
        float4 b1 = ok ? *(const float4*)&bd[c + 4]   : z4;
        sx2 += d4(a0, a0) + d4(a1, a1);
        xb  += d4(a0, b0) + d4(a1, b1);
        float tmp[8] = {a0.x, a0.y, a0.z, a0.w, a1.x, a1.y, a1.z, a1.w};
        short8 a7 = pack8(tmp);
        #pragma unroll
        for (int t = 0; t < 4; ++t) {
            short8 bfr = *(const short8*)&Wb16[(t * 16 + mm) * 800 + c];
            acc[t] = __builtin_amdgcn_mfma_f32_16x16x32_bf16(a7, bfr, acc[t], 0, 0, 0);
        }
    }
    // per-(row, wave) reductions and LDS staging
    sx2 += __shfl_xor(sx2, 16, 64); sx2 += __shfl_xor(sx2, 32, 64);
    xb  += __shfl_xor(xb, 16, 64);  xb  += __shfl_xor(xb, 32, 64);
    #pragma unroll
    for (int t = 0; t < 4; ++t)
        #pragma unroll
        for (int r = 0; r < 4; ++r)
            XWp[wid][q * 4 + r][t * 16 + mm] = acc[t][r];
    if (q == 0) { sxp[wid][mm] = sx2; xbp[wid][mm] = xb; }
    __syncthreads();
    if (wid != 0) return;

    // ---- phase 2 (wave 0 only) ----
    const int arow = row0 + mm;
    const int v0 = q * 8, v1 = 32 + q * 8;
    float mu[16], ls[16], ep[16];
    *(float4*)&mu[0]  = *(const float4*)&qmu[arow * 64 + v0];
    *(float4*)&mu[4]  = *(const float4*)&qmu[arow * 64 + v0 + 4];
    *(float4*)&mu[8]  = *(const float4*)&qmu[arow * 64 + v1];
    *(float4*)&mu[12] = *(const float4*)&qmu[arow * 64 + v1 + 4];
    *(float4*)&ls[0]  = *(const float4*)&qls[arow * 64 + v0];
    *(float4*)&ls[4]  = *(const float4*)&qls[arow * 64 + v0 + 4];
    *(float4*)&ls[8]  = *(const float4*)&qls[arow * 64 + v1];
    *(float4*)&ls[12] = *(const float4*)&qls[arow * 64 + v1 + 4];
    *(float4*)&ep[0]  = *(const float4*)&eps[arow * 64 + v0];
    *(float4*)&ep[4]  = *(const float4*)&eps[arow * 64 + v0 + 4];
    *(float4*)&ep[8]  = *(const float4*)&eps[arow * 64 + v1];
    *(float4*)&ep[12] = *(const float4*)&eps[arow * 64 + v1 + 4];

    float zf[16], qsv[16], ls_sum = 0.f;
    #pragma unroll
    for (int j = 0; j < 16; ++j) {
        qsv[j] = __expf(ls[j]);
        zf[j]  = fmaf(qsv[j], ep[j], mu[j]);
        ls_sum += ls[j];
    }
    const short8 af0 = pack8(&zf[0]), af1 = pack8(&zf[8]);

    // decoder scalars: XW combine (A-layout), z.XW, z.Wb, sxrow/xbrow
    float zxw = 0.f, zwb = 0.f;
    #pragma unroll
    for (int c2 = 0; c2 < 2; ++c2) {
        const int vb = c2 ? v1 : v0;
        #pragma unroll
        for (int j = 0; j < 8; ++j) {
            float xwv = XWp[0][mm][vb + j] + XWp[1][mm][vb + j]
                      + XWp[2][mm][vb + j] + XWp[3][mm][vb + j];
            zxw = fmaf(zf[c2 * 8 + j], xwv, zxw);
        }
        float4 wb0 = *(const float4*)&Wbv[vb];
        float4 wb1 = *(const float4*)&Wbv[vb + 4];
        zwb += zf[c2*8+0]*wb0.x + zf[c2*8+1]*wb0.y + zf[c2*8+2]*wb0.z + zf[c2*8+3]*wb0.w
             + zf[c2*8+4]*wb1.x + zf[c2*8+5]*wb1.y + zf[c2*8+6]*wb1.z + zf[c2*8+7]*wb1.w;
    }
    zxw += __shfl_xor(zxw, 16, 64); zxw += __shfl_xor(zxw, 32, 64);
    zwb += __shfl_xor(zwb, 16, 64); zwb += __shfl_xor(zwb, 32, 64);
    const float sxrow = sxp[0][mm] + sxp[1][mm] + sxp[2][mm] + sxp[3][mm];
    const float xbrow = xbp[0][mm] + xbp[1][mm] + xbp[2][mm] + xbp[3][mm];

    // z G2 z via MFMA + LDS C->A transform (wave-local, no barrier needed)
    {
        floatx4 u[4] = {{0.f,0.f,0.f,0.f},{0.f,0.f,0.f,0.f},{0.f,0.f,0.f,0.f},{0.f,0.f,0.f,0.f}};
        #pragma unroll
        for (int t = 0; t < 4; ++t) {
            short8 g0 = *(const short8*)&G2[(t * 16 + mm) * 64 + v0];
            short8 g1 = *(const short8*)&G2[(t * 16 + mm) * 64 + v1];
            u[t] = __builtin_amdgcn_mfma_f32_16x16x32_bf16(af0, g0, u[t], 0, 0, 0);
            u[t] = __builtin_amdgcn_mfma_f32_16x16x32_bf16(af1, g1, u[t], 0, 0, 0);
        }
        #pragma unroll
        for (int t = 0; t < 4; ++t)
            #pragma unroll
            for (int r = 0; r < 4; ++r)
                us[q * 4 + r][t * 16 + mm] = u[t][r];
    }
    float zg2 = 0.f;
    #pragma unroll
    for (int j = 0; j < 8; ++j) {
        zg2 = fmaf(zf[j],     us[mm][v0 + j], zg2);
        zg2 = fmaf(zf[8 + j], us[mm][v1 + j], zg2);
    }
    zg2 += __shfl_xor(zg2, 16, 64); zg2 += __shfl_xor(zg2, 32, 64);

    // ---- mixture ----
    float zz[16], zm[16], q2[16], qm[16];
    #pragma unroll
    for (int j = 0; j < 16; ++j) {
        zz[j] = zf[j] * zf[j];
        zm[j] = -2.f * zf[j];
        q2[j] = fmaf(mu[j], mu[j], qsv[j] * qsv[j]);
        qm[j] = -2.f * mu[j];
    }
    float sls = ls_sum;
    sls += __shfl_xor(sls, 16, 64); sls += __shfl_xor(sls, 32, 64);

    const short8 az2_0 = pack8(&zz[0]), az2_1 = pack8(&zz[8]);
    const short8 azm_0 = pack8(&zm[0]), azm_1 = pack8(&zm[8]);
    const short8 aq2_0 = pack8(&q2[0]), aq2_1 = pack8(&q2[8]);
    const short8 aqm_0 = pack8(&qm[0]), aqm_1 = pack8(&qm[8]);

    floatx4 acc_a[4], acc_c[4];
    float skv[4], gkv[4];
    #pragma unroll
    for (int t = 0; t < 4; ++t) {
        const int kc = t * 16 + mm;
        short8 bi0 = *(const short8*)&Bi2[kc * 64 + v0];
        short8 bi1 = *(const short8*)&Bi2[kc * 64 + v1];
        short8 bm0 = *(const short8*)&Bm1[kc * 64 + v0];
        short8 bm1 = *(const short8*)&Bm1[kc * 64 + v1];
        skv[t] = Sk[kc];
        gkv[t] = Gk[kc];
        floatx4 ca = {0.f, 0.f, 0.f, 0.f};
        ca = __builtin_amdgcn_mfma_f32_16x16x32_bf16(az2_0, bi0, ca, 0, 0, 0);
        ca = __builtin_amdgcn_mfma_f32_16x16x32_bf16(az2_1, bi1, ca, 0, 0, 0);
        ca = __builtin_amdgcn_mfma_f32_16x16x32_bf16(azm_0, bm0, ca, 0, 0, 0);
        ca = __builtin_amdgcn_mfma_f32_16x16x32_bf16(azm_1, bm1, ca, 0, 0, 0);
        acc_a[t] = ca;
        floatx4 cc = {0.f, 0.f, 0.f, 0.f};
        cc = __builtin_amdgcn_mfma_f32_16x16x32_bf16(aq2_0, bi0, cc, 0, 0, 0);
        cc = __builtin_amdgcn_mfma_f32_16x16x32_bf16(aq2_1, bi1, cc, 0, 0, 0);
        cc = __builtin_amdgcn_mfma_f32_16x16x32_bf16(aqm_0, bm0, cc, 0, 0, 0);
        cc = __builtin_amdgcn_mfma_f32_16x16x32_bf16(aqm_1, bm1, cc, 0, 0, 0);
        acc_c[t] = cc;
    }

    float comp[4][4], pz[4][4];
    #pragma unroll
    for (int t = 0; t < 4; ++t) {
        const float ck = -skv[t] - 32.0f * LOG2PI_F;
        #pragma unroll
        for (int r = 0; r < 4; ++r) {
            comp[t][r] = ck - (acc_a[t][r] + gkv[t]);
            pz[t][r] = comp[t][r] + __logf(pi[(row0 + q * 4 + r) * 64 + t * 16 + mm]);
        }
    }

    float kly = 0.f, klz = 0.f;
    #pragma unroll
    for (int r = 0; r < 4; ++r) {
        float mx = fmaxf(fmaxf(pz[0][r], pz[1][r]), fmaxf(pz[2][r], pz[3][r]));
        #pragma unroll
        for (int o = 1; o <= 8; o <<= 1) mx = fmaxf(mx, __shfl_xor(mx, o, 64));
        float e[4];
        float s = 0.f;
        #pragma unroll
        for (int t = 0; t < 4; ++t) { e[t] = __expf(pz[t][r] - mx); s += e[t]; }
        #pragma unroll
        for (int o = 1; o <= 8; o <<= 1) s += __shfl_xor(s, o, 64);
        const float lse = mx + __logf(s);
        const float inv = __frcp_rn(s);
        const float sqr = __shfl(sls, q * 4 + r, 64);
        #pragma unroll
        for (int t = 0; t < 4; ++t) {
            const float p = e[t] * inv;
            kly = fmaf(p, comp[t][r] - lse, kly);
            klz = fmaf(p, skv[t] - sqr + acc_c[t][r] + gkv[t] - 32.0f, klz);
        }
    }

    // decoder row term: sum_j (x - mean)^2 for this row
    const float dec_row = sxrow - 2.f * (zxw + xbrow) + zg2 + 2.f * zwb + sb2p[0];
    float dsum = (q == 0) ? dec_row : 0.f;
    dsum = wave_sum(dsum);
    kly = wave_sum(kly);
    klz = wave_sum(klz);
    if (lane == 0) {
        dec_p[blockIdx.x] = -0.5f * dsum;
        kly_p[blockIdx.x] = kly;
        klz_p[blockIdx.x] = klz;
    }
}

__global__ __launch_bounds__(256) void finalize_kernel(
    const float* __restrict__ dec_p, const float* __restrict__ kly_p,
    const float* __restrict__ klz_p, float* __restrict__ out)
{
    __shared__ double s0[256], s1[256], s2[256];
    const int tid = threadIdx.x;
    double a0 = 0.0, a1 = 0.0, a2 = 0.0;
    #pragma unroll
    for (int i = 0; i < 4; ++i) {
        a0 += (double)dec_p[tid + 256 * i];
        a1 += (double)kly_p[tid + 256 * i];
        a2 += (double)klz_p[tid + 256 * i];
    }
    s0[tid] = a0; s1[tid] = a1; s2[tid] = a2;
    __syncthreads();
    #pragma unroll
    for (int off = 128; off > 0; off >>= 1) {
        if (tid < off) {
            s0[tid] += s0[tid + off];
            s1[tid] += s1[tid + off];
            s2[tid] += s2[tid + off];
        }
        __syncthreads();
    }
    if (tid == 0) {
        double lpx = s0[0] - 0.5 * 1.8378770664093453 * (double)NB * (double)XD;
        out[0] = (float)((lpx - s1[0] - s2[0]) / (double)NB);
    }
}

extern "C" void kernel_launch(void* const* d_in, const int* in_sizes, int n_in,
                              void* d_out, int out_size, void* d_ws, size_t ws_size,
                              hipStream_t stream) {
    const float* x    = (const float*)d_in[0];
    const float* pi   = (const float*)d_in[1];
    const float* qmu  = (const float*)d_in[2];
    const float* qls  = (const float*)d_in[3];
    const float* eps  = (const float*)d_in[4];
    const float* pmu  = (const float*)d_in[5];
    const float* plog = (const float*)d_in[6];
    const float* W    = (const float*)d_in[7];
    const float* bd   = (const float*)d_in[8];
    float* out = (float*)d_out;

    char* ws = (char*)d_ws;
    unsigned short* Wb16 = (unsigned short*)(ws);
    unsigned short* G2   = (unsigned short*)(ws + 102400);
    unsigned short* Bi2  = (unsigned short*)(ws + 110592);
    unsigned short* Bm1  = (unsigned short*)(ws + 118784);
    float* Sk    = (float*)(ws + 126976);
    float* Gk    = (float*)(ws + 127232);
    float* Wbv   = (float*)(ws + 127488);
    float* sb2   = (float*)(ws + 127744);
    float* dec_p = (float*)(ws + 127808);
    float* kly_p = (float*)(ws + 131904);
    float* klz_p = (float*)(ws + 136000);

    prep1_kernel<<<202, 256, 0, stream>>>(W, pmu, plog, bd, Wb16, Bi2, Bm1, Sk, Gk, Wbv, sb2);
    prep2_kernel<<<16, 64, 0, stream>>>(Wb16, G2);
    mega_kernel<<<NB / 16, 256, 0, stream>>>(x, pi, qmu, qls, eps, bd,
                                             Wb16, G2, Bi2, Bm1, Sk, Gk, Wbv, sb2,
                                             dec_p, kly_p, klz_p);
    finalize_kernel<<<1, 256, 0, stream>>>(dec_p, kly_p, klz_p, out);
}